// Round 22
// baseline (869.964 us; speedup 1.0000x reference)
//
#include <hip/hip_runtime.h>
#include <hip/hip_bf16.h>

#define HW 65536
#define IMG 256
static constexpr int CDIM = 192;

typedef __attribute__((ext_vector_type(8))) short short8;
typedef __attribute__((ext_vector_type(4))) short s16x4;
typedef __attribute__((ext_vector_type(4))) float f32x4;
typedef __attribute__((ext_vector_type(2))) float f32x2;

// per-batch element strides (z within a pair = blockIdx.z)
static constexpr size_t BS_X   = (size_t)CDIM * HW;  // f32 input
static constexpr size_t BS_XT  = (size_t)HW * 192;   // bf16
static constexpr size_t BS_QKV = (size_t)576 * HW;   // bf16
static constexpr size_t BS_KV  = (size_t)384 * HW;   // bf16
static constexpr size_t BS_S   = (size_t)192 * HW;   // bf16
static constexpr size_t BS_OUT = (size_t)192 * HW;   // f32

static __device__ __forceinline__ float b2f(unsigned short u) {
    union { unsigned u; float f; } t; t.u = ((unsigned)u) << 16; return t.f;
}
static __device__ __forceinline__ unsigned short f2bu(float f) {
    __hip_bfloat16 h = __float2bfloat16(f);
    return *reinterpret_cast<unsigned short*>(&h);
}

// ---------------- pack weights fp32 -> bf16 ---------------------------------
__global__ void pack_weights(const float* __restrict__ wq,
                             const float* __restrict__ wkv,
                             const float* __restrict__ wp,
                             __hip_bfloat16* __restrict__ Wqkv,
                             __hip_bfloat16* __restrict__ Wp) {
    int i = blockIdx.x * 256 + threadIdx.x;
    if (i < 36864) Wqkv[i] = __float2bfloat16(wq[i]);
    else if (i < 110592) Wqkv[i] = __float2bfloat16(wkv[i - 36864]);
    else if (i < 147456) Wp[i - 110592] = __float2bfloat16(wp[i - 110592]);
}

// ---------------- transpose + convert: x[c][p] f32 -> xT[p][c] bf16 ---------
__global__ void transpose_cvt(const float* __restrict__ x,
                              __hip_bfloat16* __restrict__ xT) {
    __shared__ float tile[32][33];
    x  += (size_t)blockIdx.z * BS_X;
    xT += (size_t)blockIdx.z * BS_XT;
    const int p0 = blockIdx.x * 32, c0 = blockIdx.y * 32;
    const int tx = threadIdx.x & 31, ty = threadIdx.x >> 5;
#pragma unroll
    for (int r = 0; r < 4; r++)
        tile[ty + r * 8][tx] = x[(size_t)(c0 + ty + r * 8) * HW + p0 + tx];
    __syncthreads();
    const int pl = threadIdx.x >> 3, cl = (threadIdx.x & 7) * 4;
    union { unsigned short h[4]; unsigned long long u; } ob;
#pragma unroll
    for (int e = 0; e < 4; e++) ob.h[e] = f2bu(tile[cl + e][pl]);
    *(unsigned long long*)(xT + (size_t)(p0 + pl) * 192 + c0 + cl) = ob.u;
}

// ---------------- MFMA GEMM v2: stage Bs ONCE, loop all 9 m-tiles ----------
// Amortizes B-staging 9x (was grid.x=9 blocks each re-staging the same Bs).
// A [576][192] bf16 (L2-resident), Bt [HW][192] bf16, Y [576][HW] bf16.
// grid (HW/64, 1, z), block 256 = 4 waves. Bit-identical per-output math.
__global__ void gemm_bf16(const __hip_bfloat16* __restrict__ A,
                          const __hip_bfloat16* __restrict__ Bt,
                          __hip_bfloat16* __restrict__ Y) {
    __shared__ short Bs[64][200];
    Bt += (size_t)blockIdx.z * BS_XT;
    Y  += (size_t)blockIdx.z * BS_QKV;
    const int tid = threadIdx.x;
    const int wid = tid >> 6, lane = tid & 63;
    const int nBase = blockIdx.x * 64;

#pragma unroll
    for (int l = 0; l < 6; l++) {
        int ch = tid + l * 256;
        int row = ch / 24, cc = ch % 24;
        short8 v = *(const short8*)(Bt + (size_t)(nBase + row) * 192 + cc * 8);
        *(short8*)&Bs[row][cc * 8] = v;
    }
    __syncthreads();

    const int lr = lane & 15, lg = lane >> 4;
    // preload B fragments once (16 VGPR-quads); reused across all 9 m-tiles
    short8 bfr[6][4];
#pragma unroll
    for (int ks = 0; ks < 6; ks++)
#pragma unroll
        for (int f = 0; f < 4; f++)
            bfr[ks][f] = *(const short8*)&Bs[f * 16 + lr][ks * 32 + lg * 8];

    for (int mb = 0; mb < 9; mb++) {
        const int mBase = mb * 64;
        const __hip_bfloat16* Ab =
            A + (size_t)(mBase + wid * 16 + lr) * 192 + lg * 8;
        f32x4 acc[4];
#pragma unroll
        for (int f = 0; f < 4; f++) acc[f] = (f32x4){0.f, 0.f, 0.f, 0.f};

#pragma unroll
        for (int ks = 0; ks < 6; ks++) {
            short8 af = *(const short8*)(Ab + ks * 32);
#pragma unroll
            for (int f = 0; f < 4; f++)
                acc[f] = __builtin_amdgcn_mfma_f32_16x16x32_bf16(af, bfr[ks][f], acc[f], 0, 0, 0);
        }

        const int mrow = mBase + wid * 16 + lg * 4;
#pragma unroll
        for (int f = 0; f < 4; f++) {
            int n = nBase + f * 16 + lr;
#pragma unroll
            for (int r = 0; r < 4; r++)
                Y[(size_t)(mrow + r) * HW + n] = __float2bfloat16(acc[f][r]);
        }
    }
}

// ---------------- Depthwise 7x7 v8b: 4 y-tiles/block, reg prefetch ----------
__global__ __launch_bounds__(256) void dwconv7_v8(
    const __hip_bfloat16* __restrict__ in,
    const float* __restrict__ wdw,
    const float* __restrict__ bias,
    __hip_bfloat16* __restrict__ out) {
    __shared__ unsigned short tile[70][136];   // 19,040 B
    in  += (size_t)blockIdx.z * BS_QKV;
    out += (size_t)blockIdx.z * BS_KV;
    const int c = blockIdx.y;
    const int x0 = blockIdx.x * 128;
    const __hip_bfloat16* src = in + (size_t)c * HW;

    float w49[49];
#pragma unroll
    for (int i = 0; i < 49; i++) w49[i] = wdw[c * 49 + i];   // uniform -> SGPR
    const float bval = bias[c];

    const int tid = threadIdx.x;
    short8 pre[5];

    auto load_tasks = [&](int t) {
#pragma unroll
        for (int l = 0; l < 5; l++) {
            int idx = tid + l * 256;
            short8 v = (short8){0, 0, 0, 0, 0, 0, 0, 0};
            if (idx < 70 * 17) {
                int r = idx / 17, cs = idx - r * 17;
                int gy = t * 64 + r - 3;
                int gxb = x0 + cs * 8 - 3;
                if ((unsigned)gy < IMG && gxb >= 0 && gxb + 8 <= IMG) {
                    v = *(const short8*)(src + gy * IMG + gxb);
                } else if ((unsigned)gy < IMG) {
#pragma unroll
                    for (int e = 0; e < 8; e++) {
                        int gx = gxb + e;
                        if ((unsigned)gx < IMG)
                            v[e] = *(const short*)(src + gy * IMG + gx);
                    }
                }
            }
            pre[l] = v;
        }
    };

    load_tasks(0);

    const int tx4 = (tid & 31) * 4;
    const int gy8 = (tid >> 5) * 8;

    for (int t = 0; t < 4; t++) {
        __syncthreads();
#pragma unroll
        for (int l = 0; l < 5; l++) {
            int idx = tid + l * 256;
            if (idx < 70 * 17) {
                int r = idx / 17, cs = idx - r * 17;
                *(short8*)&tile[r][cs * 8] = pre[l];
            }
        }
        __syncthreads();
        if (t < 3) load_tasks(t + 1);

        f32x2 acc2[8][2];
#pragma unroll
        for (int j = 0; j < 8; j++) {
            acc2[j][0] = (f32x2){bval, bval};
            acc2[j][1] = (f32x2){bval, bval};
        }

#pragma unroll
        for (int rr = 0; rr < 14; rr++) {
            const unsigned short* rowp = &tile[gy8 + rr][tx4];
            s16x4 a0 = *(const s16x4*)(rowp);
            s16x4 a1 = *(const s16x4*)(rowp + 4);
            s16x4 a2 = *(const s16x4*)(rowp + 8);
            float win[12];
#pragma unroll
            for (int e = 0; e < 4; e++) {
                win[e]     = b2f((unsigned short)a0[e]);
                win[e + 4] = b2f((unsigned short)a1[e]);
                win[e + 8] = b2f((unsigned short)a2[e]);
            }
#pragma unroll
            for (int j = 0; j < 8; j++) {
                const int ky = rr - j;
                if (ky >= 0 && ky < 7) {
#pragma unroll
                    for (int kx = 0; kx < 7; kx++) {
                        const float w = w49[ky * 7 + kx];
                        const f32x2 wv = (f32x2){w, w};
                        acc2[j][0] += (f32x2){win[kx], win[kx + 1]} * wv;
                        acc2[j][1] += (f32x2){win[kx + 2], win[kx + 3]} * wv;
                    }
                }
            }
        }

        __hip_bfloat16* dst = out + (size_t)c * HW +
                              (size_t)(t * 64 + gy8) * IMG + x0 + tx4;
#pragma unroll
        for (int j = 0; j < 8; j++) {
            union { unsigned short h[4]; unsigned long long u; } ob;
            ob.h[0] = f2bu(acc2[j][0][0]);
            ob.h[1] = f2bu(acc2[j][0][1]);
            ob.h[2] = f2bu(acc2[j][1][0]);
            ob.h[3] = f2bu(acc2[j][1][1]);
            *(unsigned long long*)(dst + (size_t)j * IMG) = ob.u;
        }
    }
}

// ------------- Fused dw3x3(q) + 8x8 circ conv (v4: 4 ph-tiles + prefetch) ---
__global__ __launch_bounds__(256) void circ_qfused(
    const __hip_bfloat16* __restrict__ q0,    // pre-dw q (gemm out)
    const __hip_bfloat16* __restrict__ kbuf,  // post-dw k
    const float* __restrict__ w_qdw, const float* __restrict__ b_qdw,
    __hip_bfloat16* __restrict__ sout) {
    __shared__ float qs[10][264];
    __shared__ float qP[32][68];
    __shared__ float kP[32][68];
    q0   += (size_t)blockIdx.z * BS_QKV;
    kbuf += (size_t)blockIdx.z * BS_KV;
    sout += (size_t)blockIdx.z * BS_S;
    const int c = blockIdx.y;
    const int ph0 = blockIdx.x * 4;
    const __hip_bfloat16* qsrc = q0 + (size_t)c * HW;
    const __hip_bfloat16* ksrc = kbuf + (size_t)c * HW;
    const int tid = threadIdx.x;

    float w9[9];
#pragma unroll
    for (int i = 0; i < 9; i++) w9[i] = w_qdw[c * 9 + i];
    const float bq = b_qdw[c];

    short8 pq[2], pk;
    auto load_tile = [&](int t) {
        const int y0 = (ph0 + t) * 8;
#pragma unroll
        for (int l = 0; l < 2; l++) {
            int idx = tid + l * 256;
            short8 v = (short8){0, 0, 0, 0, 0, 0, 0, 0};
            if (idx < 320) {
                int r = idx >> 5, ch = idx & 31;
                int gy = y0 + r - 1;
                if ((unsigned)gy < IMG)
                    v = *(const short8*)(qsrc + gy * IMG + ch * 8);
            }
            pq[l] = v;
        }
        {
            int a = tid >> 5, ch = tid & 31;
            pk = *(const short8*)(ksrc + (y0 + a) * IMG + ch * 8);
        }
    };

    load_tile(0);

    const int i = tid >> 5, pw = tid & 31;

    for (int t = 0; t < 4; t++) {
        const int y0 = (ph0 + t) * 8;
        __syncthreads();
#pragma unroll
        for (int l = 0; l < 2; l++) {
            int idx = tid + l * 256;
            if (idx < 320) {
                int r = idx >> 5, ch = idx & 31;
                f32x4 lo, hi;
#pragma unroll
                for (int e = 0; e < 4; e++) {
                    lo[e] = b2f((unsigned short)pq[l][e]);
                    hi[e] = b2f((unsigned short)pq[l][4 + e]);
                }
                *(f32x4*)&qs[r][4 + ch * 8] = lo;
                *(f32x4*)&qs[r][8 + ch * 8] = hi;
            }
        }
        if (tid < 20) {
            int r = tid >> 1, s2 = tid & 1;
            qs[r][s2 ? 260 : 3] = 0.f;
        }
        {
            int a = tid >> 5, ch = tid & 31;
            f32x4 lo, hi;
#pragma unroll
            for (int e = 0; e < 4; e++) {
                lo[e] = b2f((unsigned short)pk[e]);
                hi[e] = b2f((unsigned short)pk[4 + e]);
            }
            *(f32x4*)&kP[ch][a * 8] = lo;
            *(f32x4*)&kP[ch][a * 8 + 4] = hi;
        }
        __syncthreads();
        if (t < 3) load_tile(t + 1);

        {
            const int x = tid;
            float accq[8];
#pragma unroll
            for (int j = 0; j < 8; j++) accq[j] = bq;
#pragma unroll
            for (int kx = 0; kx < 3; kx++)
#pragma unroll
                for (int yy = 0; yy < 10; yy++) {
                    float vv = qs[yy][x + kx + 3];
#pragma unroll
                    for (int j = 0; j < 8; j++) {
                        int ky = yy - j;
                        if (ky >= 0 && ky < 3) accq[j] += vv * w9[ky * 3 + kx];
                    }
                }
#pragma unroll
            for (int j = 0; j < 8; j++) qP[x >> 3][j * 8 + (x & 7)] = accq[j];
        }
        __syncthreads();

        float qv[8][8];
#pragma unroll
        for (int a = 0; a < 8; a++) {
            f32x4 u0 = *(const f32x4*)&qP[pw][a * 8];
            f32x4 u1 = *(const f32x4*)&qP[pw][a * 8 + 4];
            qv[a][0] = u0[0]; qv[a][1] = u0[1]; qv[a][2] = u0[2]; qv[a][3] = u0[3];
            qv[a][4] = u1[0]; qv[a][5] = u1[1]; qv[a][6] = u1[2]; qv[a][7] = u1[3];
        }
        f32x2 acc2[4];
#pragma unroll
        for (int j2 = 0; j2 < 4; j2++) acc2[j2] = (f32x2){0.f, 0.f};

#pragma unroll
        for (int a = 0; a < 8; a++) {
            const int r = (i - a + 8) & 7;
            f32x4 k0v = *(const f32x4*)&kP[pw][r * 8];
            f32x4 k1v = *(const f32x4*)&kP[pw][r * 8 + 4];
            const float kr[8] = {k0v[0], k0v[1], k0v[2], k0v[3],
                                 k1v[0], k1v[1], k1v[2], k1v[3]};
            const f32x2 krE[4] = {(f32x2){kr[0], kr[1]}, (f32x2){kr[2], kr[3]},
                                  (f32x2){kr[4], kr[5]}, (f32x2){kr[6], kr[7]}};
            const f32x2 krS[4] = {(f32x2){kr[1], kr[2]}, (f32x2){kr[3], kr[4]},
                                  (f32x2){kr[5], kr[6]}, (f32x2){kr[7], kr[0]}};
#pragma unroll
            for (int b = 0; b < 8; b += 2) {
                const float qe = qv[a][b];
                const float qo = qv[a][b + 1];
#pragma unroll
                for (int j2 = 0; j2 < 4; j2++) {
                    const int re = (2 * j2 - b + 8) & 7;
                    acc2[j2] += (f32x2){qe, qe} * krE[re >> 1];
                    const int ro = (2 * j2 - b - 1 + 16) & 7;
                    acc2[j2] += (f32x2){qo, qo} * krS[(ro - 1) >> 1];
                }
            }
        }
        union { unsigned short h[8]; short8 s8; } ob;
#pragma unroll
        for (int j = 0; j < 8; j++) ob.h[j] = f2bu(acc2[j >> 1][j & 1]);
        *(short8*)(sout + (size_t)c * HW + (size_t)(y0 + i) * IMG + pw * 8) = ob.s8;
    }
}

// ------------- Fused: LN(ch)+affine, *v, proj GEMM + bias (px-128, proven) --
__global__ __launch_bounds__(256, 2) void gemm_proj_ln(
    const __hip_bfloat16* __restrict__ Wp,
    const __hip_bfloat16* __restrict__ s,
    const __hip_bfloat16* __restrict__ v,
    const float* __restrict__ ln_w, const float* __restrict__ ln_b,
    const float* __restrict__ bias,
    float* __restrict__ Y) {
    __shared__ short Bs[128][200];
    __shared__ float red[2][2][128];
    __shared__ float muA[128], rsA[128];
    s += (size_t)blockIdx.z * BS_S;
    v += (size_t)blockIdx.z * BS_KV;
    Y += (size_t)blockIdx.z * BS_OUT;
    const int tid = threadIdx.x;
    const int p0 = blockIdx.x * 128;
    const int px = tid & 127, h = tid >> 7;
    const unsigned short* sp = (const unsigned short*)s;

    float sum = 0.f, sq = 0.f;
#pragma unroll 4
    for (int l = 0; l < 48; l++) {
        int c = h * 96 + l * 2;
        unsigned short ua = sp[(size_t)c * HW + p0 + px];
        unsigned short ub = sp[(size_t)(c + 1) * HW + p0 + px];
        float a = b2f(ua), b = b2f(ub);
        sum += a + b;
        sq += a * a + b * b;
        *(unsigned*)&Bs[px][c] = (unsigned)ua | ((unsigned)ub << 16);
    }
    red[h][0][px] = sum;
    red[h][1][px] = sq;
    __syncthreads();
    if (tid < 128) {
        float sm = red[0][0][tid] + red[1][0][tid];
        float sQ = red[0][1][tid] + red[1][1][tid];
        float mu = sm * (1.f / 192.f);
        float var = sQ * (1.f / 192.f) - mu * mu;
        muA[tid] = mu;
        rsA[tid] = rsqrtf(var + 1e-5f);
    }
    __syncthreads();

    const float mu = muA[px], rs = rsA[px];
#pragma unroll 4
    for (int l = 0; l < 48; l++) {
        int c = h * 96 + l * 2;
        unsigned pr = *(unsigned*)&Bs[px][c];
        float a = b2f((unsigned short)pr);
        float b = b2f((unsigned short)(pr >> 16));
        float va = b2f(*(const unsigned short*)(v + (size_t)c * HW + p0 + px));
        float vb = b2f(*(const unsigned short*)(v + (size_t)(c + 1) * HW + p0 + px));
        a = ((a - mu) * rs * ln_w[c] + ln_b[c]) * va;
        b = ((b - mu) * rs * ln_w[c + 1] + ln_b[c + 1]) * vb;
        *(unsigned*)&Bs[px][c] = (unsigned)f2bu(a) | ((unsigned)f2bu(b) << 16);
    }
    __syncthreads();

    const int wid = tid >> 6, lane = tid & 63;
    const int lr = lane & 15, lg = lane >> 4;
    f32x4 acc[3][8];
#pragma unroll
    for (int mf = 0; mf < 3; mf++)
#pragma unroll
        for (int f = 0; f < 8; f++) acc[mf][f] = (f32x4){0.f, 0.f, 0.f, 0.f};

#pragma unroll
    for (int ks = 0; ks < 6; ks++) {
        short8 bfr[8];
#pragma unroll
        for (int f = 0; f < 8; f++)
            bfr[f] = *(const short8*)&Bs[f * 16 + lr][ks * 32 + lg * 8];
#pragma unroll
        for (int mf = 0; mf < 3; mf++) {
            int mrow = wid * 48 + mf * 16 + lr;
            short8 af = *(const short8*)(Wp + (size_t)mrow * 192 + ks * 32 + lg * 8);
#pragma unroll
            for (int f = 0; f < 8; f++)
                acc[mf][f] = __builtin_amdgcn_mfma_f32_16x16x32_bf16(af, bfr[f], acc[mf][f], 0, 0, 0);
        }
    }

#pragma unroll
    for (int mf = 0; mf < 3; mf++) {
        int m0 = wid * 48 + mf * 16 + lg * 4;
#pragma unroll
        for (int f = 0; f < 8; f++) {
            int n = p0 + f * 16 + lr;
#pragma unroll
            for (int r = 0; r < 4; r++)
                Y[(size_t)(m0 + r) * HW + n] = acc[mf][f][r] + bias[m0 + r];
        }
    }
}

extern "C" void kernel_launch(void* const* d_in, const int* in_sizes, int n_in,
                              void* d_out, int out_size, void* d_ws, size_t ws_size,
                              hipStream_t stream) {
    const float* x      = (const float*)d_in[0];
    const float* wq     = (const float*)d_in[1];
    const float* w_qdw  = (const float*)d_in[2];
    const float* b_qdw  = (const float*)d_in[3];
    const float* wkv    = (const float*)d_in[4];
    const float* w_kvdw = (const float*)d_in[5];
    const float* b_kvdw = (const float*)d_in[6];
    const float* ln_w   = (const float*)d_in[7];
    const float* ln_b   = (const float*)d_in[8];
    const float* w_proj = (const float*)d_in[9];
    const float* b_proj = (const float*)d_in[10];
    float* out = (float*)d_out;
    char* ws = (char*)d_ws;

    // Pair-batched (z=2) ws layout, ~353 MB (ws_size >= 604 MB proven r7):
    __hip_bfloat16* qkv0  = (__hip_bfloat16*)(ws + 0);
    __hip_bfloat16* kvbuf = (__hip_bfloat16*)(ws + 150994944ull);
    __hip_bfloat16* sbuf  = (__hip_bfloat16*)(ws + 251658240ull);
    __hip_bfloat16* xT    = (__hip_bfloat16*)(ws + 301989888ull);
    __hip_bfloat16* Wqkv  = (__hip_bfloat16*)(ws + 352321536ull);
    __hip_bfloat16* Wp    = Wqkv + 110592;

    pack_weights<<<576, 256, 0, stream>>>(wq, wkv, w_proj, Wqkv, Wp);

    for (int p = 0; p < 2; p++) {
        const float* xp = x + (size_t)(p * 2) * BS_X;
        float* outp = out + (size_t)(p * 2) * BS_OUT;
        transpose_cvt<<<dim3(HW / 32, 6, 2), 256, 0, stream>>>(xp, xT);
        gemm_bf16<<<dim3(HW / 64, 1, 2), 256, 0, stream>>>(Wqkv, xT, qkv0);
        dwconv7_v8<<<dim3(2, 384, 2), 256, 0, stream>>>(qkv0 + (size_t)192 * HW,
                                                        w_kvdw, b_kvdw, kvbuf);
        circ_qfused<<<dim3(8, 192, 2), 256, 0, stream>>>(qkv0, kvbuf,
                                                         w_qdw, b_qdw, sbuf);
        gemm_proj_ln<<<dim3(HW / 128, 1, 2), 256, 0, stream>>>(
            Wp, sbuf, kvbuf + (size_t)192 * HW, ln_w, ln_b, b_proj, outp);
    }
}

// Round 23
// 637.708 us; speedup vs baseline: 1.3642x; 1.3642x over previous
//
#include <hip/hip_runtime.h>
#include <hip/hip_bf16.h>

#define HW 65536
#define IMG 256
static constexpr int CDIM = 192;

typedef __attribute__((ext_vector_type(8))) short short8;
typedef __attribute__((ext_vector_type(4))) short s16x4;
typedef __attribute__((ext_vector_type(4))) float f32x4;
typedef __attribute__((ext_vector_type(2))) float f32x2;

// per-batch element strides (z within a pair = blockIdx.z)
static constexpr size_t BS_X   = (size_t)CDIM * HW;  // f32 input
static constexpr size_t BS_XT  = (size_t)HW * 192;   // bf16
static constexpr size_t BS_QKV = (size_t)576 * HW;   // bf16
static constexpr size_t BS_KV  = (size_t)384 * HW;   // bf16
static constexpr size_t BS_S   = (size_t)192 * HW;   // bf16
static constexpr size_t BS_OUT = (size_t)192 * HW;   // f32

static __device__ __forceinline__ float b2f(unsigned short u) {
    union { unsigned u; float f; } t; t.u = ((unsigned)u) << 16; return t.f;
}
static __device__ __forceinline__ unsigned short f2bu(float f) {
    __hip_bfloat16 h = __float2bfloat16(f);
    return *reinterpret_cast<unsigned short*>(&h);
}

// ---------------- pack weights fp32 -> bf16 ---------------------------------
__global__ void pack_weights(const float* __restrict__ wq,
                             const float* __restrict__ wkv,
                             const float* __restrict__ wp,
                             __hip_bfloat16* __restrict__ Wqkv,
                             __hip_bfloat16* __restrict__ Wp) {
    int i = blockIdx.x * 256 + threadIdx.x;
    if (i < 36864) Wqkv[i] = __float2bfloat16(wq[i]);
    else if (i < 110592) Wqkv[i] = __float2bfloat16(wkv[i - 36864]);
    else if (i < 147456) Wp[i - 110592] = __float2bfloat16(wp[i - 110592]);
}

// ---------------- transpose + convert: x[c][p] f32 -> xT[p][c] bf16 ---------
__global__ void transpose_cvt(const float* __restrict__ x,
                              __hip_bfloat16* __restrict__ xT) {
    __shared__ float tile[32][33];
    x  += (size_t)blockIdx.z * BS_X;
    xT += (size_t)blockIdx.z * BS_XT;
    const int p0 = blockIdx.x * 32, c0 = blockIdx.y * 32;
    const int tx = threadIdx.x & 31, ty = threadIdx.x >> 5;
#pragma unroll
    for (int r = 0; r < 4; r++)
        tile[ty + r * 8][tx] = x[(size_t)(c0 + ty + r * 8) * HW + p0 + tx];
    __syncthreads();
    const int pl = threadIdx.x >> 3, cl = (threadIdx.x & 7) * 4;
    union { unsigned short h[4]; unsigned long long u; } ob;
#pragma unroll
    for (int e = 0; e < 4; e++) ob.h[e] = f2bu(tile[cl + e][pl]);
    *(unsigned long long*)(xT + (size_t)(p0 + pl) * 192 + c0 + cl) = ob.u;
}

// ---------------- MFMA GEMM, BN=64 (6 blocks/CU): Y = A * Bt^T, bf16 out ----
// r22 lesson: grid (9,1024) beats m-loop-in-block (write locality + TLP).
__global__ void gemm_bf16(const __hip_bfloat16* __restrict__ A,
                          const __hip_bfloat16* __restrict__ Bt,
                          __hip_bfloat16* __restrict__ Y) {
    __shared__ short Bs[64][200];
    Bt += (size_t)blockIdx.z * BS_XT;
    Y  += (size_t)blockIdx.z * BS_QKV;
    const int tid = threadIdx.x;
    const int wid = tid >> 6, lane = tid & 63;
    const int mBase = blockIdx.x * 64, nBase = blockIdx.y * 64;

#pragma unroll
    for (int l = 0; l < 6; l++) {
        int ch = tid + l * 256;
        int row = ch / 24, cc = ch % 24;
        short8 v = *(const short8*)(Bt + (size_t)(nBase + row) * 192 + cc * 8);
        *(short8*)&Bs[row][cc * 8] = v;
    }
    __syncthreads();

    const int lr = lane & 15, lg = lane >> 4;
    const __hip_bfloat16* Ab = A + (size_t)(mBase + wid * 16 + lr) * 192 + lg * 8;
    f32x4 acc[4];
#pragma unroll
    for (int f = 0; f < 4; f++) acc[f] = (f32x4){0.f, 0.f, 0.f, 0.f};

#pragma unroll
    for (int ks = 0; ks < 6; ks++) {
        short8 af = *(const short8*)(Ab + ks * 32);
#pragma unroll
        for (int f = 0; f < 4; f++) {
            short8 bfr = *(const short8*)&Bs[f * 16 + lr][ks * 32 + lg * 8];
            acc[f] = __builtin_amdgcn_mfma_f32_16x16x32_bf16(af, bfr, acc[f], 0, 0, 0);
        }
    }

    const int mrow = mBase + wid * 16 + lg * 4;
#pragma unroll
    for (int f = 0; f < 4; f++) {
        int n = nBase + f * 16 + lr;
#pragma unroll
        for (int r = 0; r < 4; r++)
            Y[(size_t)(mrow + r) * HW + n] = __float2bfloat16(acc[f][r]);
    }
}

// ---------------- Depthwise 7x7 v8b: 4 y-tiles/block, reg prefetch ----------
__global__ __launch_bounds__(256) void dwconv7_v8(
    const __hip_bfloat16* __restrict__ in,
    const float* __restrict__ wdw,
    const float* __restrict__ bias,
    __hip_bfloat16* __restrict__ out) {
    __shared__ unsigned short tile[70][136];   // 19,040 B
    in  += (size_t)blockIdx.z * BS_QKV;
    out += (size_t)blockIdx.z * BS_KV;
    const int c = blockIdx.y;
    const int x0 = blockIdx.x * 128;
    const __hip_bfloat16* src = in + (size_t)c * HW;

    float w49[49];
#pragma unroll
    for (int i = 0; i < 49; i++) w49[i] = wdw[c * 49 + i];   // uniform -> SGPR
    const float bval = bias[c];

    const int tid = threadIdx.x;
    short8 pre[5];

    auto load_tasks = [&](int t) {
#pragma unroll
        for (int l = 0; l < 5; l++) {
            int idx = tid + l * 256;
            short8 v = (short8){0, 0, 0, 0, 0, 0, 0, 0};
            if (idx < 70 * 17) {
                int r = idx / 17, cs = idx - r * 17;
                int gy = t * 64 + r - 3;
                int gxb = x0 + cs * 8 - 3;
                if ((unsigned)gy < IMG && gxb >= 0 && gxb + 8 <= IMG) {
                    v = *(const short8*)(src + gy * IMG + gxb);
                } else if ((unsigned)gy < IMG) {
#pragma unroll
                    for (int e = 0; e < 8; e++) {
                        int gx = gxb + e;
                        if ((unsigned)gx < IMG)
                            v[e] = *(const short*)(src + gy * IMG + gx);
                    }
                }
            }
            pre[l] = v;
        }
    };

    load_tasks(0);

    const int tx4 = (tid & 31) * 4;
    const int gy8 = (tid >> 5) * 8;

    for (int t = 0; t < 4; t++) {
        __syncthreads();
#pragma unroll
        for (int l = 0; l < 5; l++) {
            int idx = tid + l * 256;
            if (idx < 70 * 17) {
                int r = idx / 17, cs = idx - r * 17;
                *(short8*)&tile[r][cs * 8] = pre[l];
            }
        }
        __syncthreads();
        if (t < 3) load_tasks(t + 1);

        f32x2 acc2[8][2];
#pragma unroll
        for (int j = 0; j < 8; j++) {
            acc2[j][0] = (f32x2){bval, bval};
            acc2[j][1] = (f32x2){bval, bval};
        }

#pragma unroll
        for (int rr = 0; rr < 14; rr++) {
            const unsigned short* rowp = &tile[gy8 + rr][tx4];
            s16x4 a0 = *(const s16x4*)(rowp);
            s16x4 a1 = *(const s16x4*)(rowp + 4);
            s16x4 a2 = *(const s16x4*)(rowp + 8);
            float win[12];
#pragma unroll
            for (int e = 0; e < 4; e++) {
                win[e]     = b2f((unsigned short)a0[e]);
                win[e + 4] = b2f((unsigned short)a1[e]);
                win[e + 8] = b2f((unsigned short)a2[e]);
            }
#pragma unroll
            for (int j = 0; j < 8; j++) {
                const int ky = rr - j;
                if (ky >= 0 && ky < 7) {
#pragma unroll
                    for (int kx = 0; kx < 7; kx++) {
                        const float w = w49[ky * 7 + kx];
                        const f32x2 wv = (f32x2){w, w};
                        acc2[j][0] += (f32x2){win[kx], win[kx + 1]} * wv;
                        acc2[j][1] += (f32x2){win[kx + 2], win[kx + 3]} * wv;
                    }
                }
            }
        }

        __hip_bfloat16* dst = out + (size_t)c * HW +
                              (size_t)(t * 64 + gy8) * IMG + x0 + tx4;
#pragma unroll
        for (int j = 0; j < 8; j++) {
            union { unsigned short h[4]; unsigned long long u; } ob;
            ob.h[0] = f2bu(acc2[j][0][0]);
            ob.h[1] = f2bu(acc2[j][0][1]);
            ob.h[2] = f2bu(acc2[j][1][0]);
            ob.h[3] = f2bu(acc2[j][1][1]);
            *(unsigned long long*)(dst + (size_t)j * IMG) = ob.u;
        }
    }
}

// ------------- Fused dw3x3(q) + 8x8 circ conv (v4: 4 ph-tiles + prefetch) ---
__global__ __launch_bounds__(256) void circ_qfused(
    const __hip_bfloat16* __restrict__ q0,    // pre-dw q (gemm out)
    const __hip_bfloat16* __restrict__ kbuf,  // post-dw k
    const float* __restrict__ w_qdw, const float* __restrict__ b_qdw,
    __hip_bfloat16* __restrict__ sout) {
    __shared__ float qs[10][264];
    __shared__ float qP[32][68];
    __shared__ float kP[32][68];
    q0   += (size_t)blockIdx.z * BS_QKV;
    kbuf += (size_t)blockIdx.z * BS_KV;
    sout += (size_t)blockIdx.z * BS_S;
    const int c = blockIdx.y;
    const int ph0 = blockIdx.x * 4;
    const __hip_bfloat16* qsrc = q0 + (size_t)c * HW;
    const __hip_bfloat16* ksrc = kbuf + (size_t)c * HW;
    const int tid = threadIdx.x;

    float w9[9];
#pragma unroll
    for (int i = 0; i < 9; i++) w9[i] = w_qdw[c * 9 + i];
    const float bq = b_qdw[c];

    short8 pq[2], pk;
    auto load_tile = [&](int t) {
        const int y0 = (ph0 + t) * 8;
#pragma unroll
        for (int l = 0; l < 2; l++) {
            int idx = tid + l * 256;
            short8 v = (short8){0, 0, 0, 0, 0, 0, 0, 0};
            if (idx < 320) {
                int r = idx >> 5, ch = idx & 31;
                int gy = y0 + r - 1;
                if ((unsigned)gy < IMG)
                    v = *(const short8*)(qsrc + gy * IMG + ch * 8);
            }
            pq[l] = v;
        }
        {
            int a = tid >> 5, ch = tid & 31;
            pk = *(const short8*)(ksrc + (y0 + a) * IMG + ch * 8);
        }
    };

    load_tile(0);

    const int i = tid >> 5, pw = tid & 31;

    for (int t = 0; t < 4; t++) {
        const int y0 = (ph0 + t) * 8;
        __syncthreads();
#pragma unroll
        for (int l = 0; l < 2; l++) {
            int idx = tid + l * 256;
            if (idx < 320) {
                int r = idx >> 5, ch = idx & 31;
                f32x4 lo, hi;
#pragma unroll
                for (int e = 0; e < 4; e++) {
                    lo[e] = b2f((unsigned short)pq[l][e]);
                    hi[e] = b2f((unsigned short)pq[l][4 + e]);
                }
                *(f32x4*)&qs[r][4 + ch * 8] = lo;
                *(f32x4*)&qs[r][8 + ch * 8] = hi;
            }
        }
        if (tid < 20) {
            int r = tid >> 1, s2 = tid & 1;
            qs[r][s2 ? 260 : 3] = 0.f;
        }
        {
            int a = tid >> 5, ch = tid & 31;
            f32x4 lo, hi;
#pragma unroll
            for (int e = 0; e < 4; e++) {
                lo[e] = b2f((unsigned short)pk[e]);
                hi[e] = b2f((unsigned short)pk[4 + e]);
            }
            *(f32x4*)&kP[ch][a * 8] = lo;
            *(f32x4*)&kP[ch][a * 8 + 4] = hi;
        }
        __syncthreads();
        if (t < 3) load_tile(t + 1);

        {
            const int x = tid;
            float accq[8];
#pragma unroll
            for (int j = 0; j < 8; j++) accq[j] = bq;
#pragma unroll
            for (int kx = 0; kx < 3; kx++)
#pragma unroll
                for (int yy = 0; yy < 10; yy++) {
                    float vv = qs[yy][x + kx + 3];
#pragma unroll
                    for (int j = 0; j < 8; j++) {
                        int ky = yy - j;
                        if (ky >= 0 && ky < 3) accq[j] += vv * w9[ky * 3 + kx];
                    }
                }
#pragma unroll
            for (int j = 0; j < 8; j++) qP[x >> 3][j * 8 + (x & 7)] = accq[j];
        }
        __syncthreads();

        float qv[8][8];
#pragma unroll
        for (int a = 0; a < 8; a++) {
            f32x4 u0 = *(const f32x4*)&qP[pw][a * 8];
            f32x4 u1 = *(const f32x4*)&qP[pw][a * 8 + 4];
            qv[a][0] = u0[0]; qv[a][1] = u0[1]; qv[a][2] = u0[2]; qv[a][3] = u0[3];
            qv[a][4] = u1[0]; qv[a][5] = u1[1]; qv[a][6] = u1[2]; qv[a][7] = u1[3];
        }
        f32x2 acc2[4];
#pragma unroll
        for (int j2 = 0; j2 < 4; j2++) acc2[j2] = (f32x2){0.f, 0.f};

#pragma unroll
        for (int a = 0; a < 8; a++) {
            const int r = (i - a + 8) & 7;
            f32x4 k0v = *(const f32x4*)&kP[pw][r * 8];
            f32x4 k1v = *(const f32x4*)&kP[pw][r * 8 + 4];
            const float kr[8] = {k0v[0], k0v[1], k0v[2], k0v[3],
                                 k1v[0], k1v[1], k1v[2], k1v[3]};
            const f32x2 krE[4] = {(f32x2){kr[0], kr[1]}, (f32x2){kr[2], kr[3]},
                                  (f32x2){kr[4], kr[5]}, (f32x2){kr[6], kr[7]}};
            const f32x2 krS[4] = {(f32x2){kr[1], kr[2]}, (f32x2){kr[3], kr[4]},
                                  (f32x2){kr[5], kr[6]}, (f32x2){kr[7], kr[0]}};
#pragma unroll
            for (int b = 0; b < 8; b += 2) {
                const float qe = qv[a][b];
                const float qo = qv[a][b + 1];
#pragma unroll
                for (int j2 = 0; j2 < 4; j2++) {
                    const int re = (2 * j2 - b + 8) & 7;
                    acc2[j2] += (f32x2){qe, qe} * krE[re >> 1];
                    const int ro = (2 * j2 - b - 1 + 16) & 7;
                    acc2[j2] += (f32x2){qo, qo} * krS[(ro - 1) >> 1];
                }
            }
        }
        union { unsigned short h[8]; short8 s8; } ob;
#pragma unroll
        for (int j = 0; j < 8; j++) ob.h[j] = f2bu(acc2[j >> 1][j & 1]);
        *(short8*)(sout + (size_t)c * HW + (size_t)(y0 + i) * IMG + pw * 8) = ob.s8;
    }
}

// ------------- Fused: LN(ch)+affine, *v, proj GEMM + bias (px-128, proven) --
__global__ __launch_bounds__(256, 2) void gemm_proj_ln(
    const __hip_bfloat16* __restrict__ Wp,
    const __hip_bfloat16* __restrict__ s,
    const __hip_bfloat16* __restrict__ v,
    const float* __restrict__ ln_w, const float* __restrict__ ln_b,
    const float* __restrict__ bias,
    float* __restrict__ Y) {
    __shared__ short Bs[128][200];
    __shared__ float red[2][2][128];
    __shared__ float muA[128], rsA[128];
    s += (size_t)blockIdx.z * BS_S;
    v += (size_t)blockIdx.z * BS_KV;
    Y += (size_t)blockIdx.z * BS_OUT;
    const int tid = threadIdx.x;
    const int p0 = blockIdx.x * 128;
    const int px = tid & 127, h = tid >> 7;
    const unsigned short* sp = (const unsigned short*)s;

    float sum = 0.f, sq = 0.f;
#pragma unroll 4
    for (int l = 0; l < 48; l++) {
        int c = h * 96 + l * 2;
        unsigned short ua = sp[(size_t)c * HW + p0 + px];
        unsigned short ub = sp[(size_t)(c + 1) * HW + p0 + px];
        float a = b2f(ua), b = b2f(ub);
        sum += a + b;
        sq += a * a + b * b;
        *(unsigned*)&Bs[px][c] = (unsigned)ua | ((unsigned)ub << 16);
    }
    red[h][0][px] = sum;
    red[h][1][px] = sq;
    __syncthreads();
    if (tid < 128) {
        float sm = red[0][0][tid] + red[1][0][tid];
        float sQ = red[0][1][tid] + red[1][1][tid];
        float mu = sm * (1.f / 192.f);
        float var = sQ * (1.f / 192.f) - mu * mu;
        muA[tid] = mu;
        rsA[tid] = rsqrtf(var + 1e-5f);
    }
    __syncthreads();

    const float mu = muA[px], rs = rsA[px];
#pragma unroll 4
    for (int l = 0; l < 48; l++) {
        int c = h * 96 + l * 2;
        unsigned pr = *(unsigned*)&Bs[px][c];
        float a = b2f((unsigned short)pr);
        float b = b2f((unsigned short)(pr >> 16));
        float va = b2f(*(const unsigned short*)(v + (size_t)c * HW + p0 + px));
        float vb = b2f(*(const unsigned short*)(v + (size_t)(c + 1) * HW + p0 + px));
        a = ((a - mu) * rs * ln_w[c] + ln_b[c]) * va;
        b = ((b - mu) * rs * ln_w[c + 1] + ln_b[c + 1]) * vb;
        *(unsigned*)&Bs[px][c] = (unsigned)f2bu(a) | ((unsigned)f2bu(b) << 16);
    }
    __syncthreads();

    const int wid = tid >> 6, lane = tid & 63;
    const int lr = lane & 15, lg = lane >> 4;
    f32x4 acc[3][8];
#pragma unroll
    for (int mf = 0; mf < 3; mf++)
#pragma unroll
        for (int f = 0; f < 8; f++) acc[mf][f] = (f32x4){0.f, 0.f, 0.f, 0.f};

#pragma unroll
    for (int ks = 0; ks < 6; ks++) {
        short8 bfr[8];
#pragma unroll
        for (int f = 0; f < 8; f++)
            bfr[f] = *(const short8*)&Bs[f * 16 + lr][ks * 32 + lg * 8];
#pragma unroll
        for (int mf = 0; mf < 3; mf++) {
            int mrow = wid * 48 + mf * 16 + lr;
            short8 af = *(const short8*)(Wp + (size_t)mrow * 192 + ks * 32 + lg * 8);
#pragma unroll
            for (int f = 0; f < 8; f++)
                acc[mf][f] = __builtin_amdgcn_mfma_f32_16x16x32_bf16(af, bfr[f], acc[mf][f], 0, 0, 0);
        }
    }

#pragma unroll
    for (int mf = 0; mf < 3; mf++) {
        int m0 = wid * 48 + mf * 16 + lg * 4;
#pragma unroll
        for (int f = 0; f < 8; f++) {
            int n = p0 + f * 16 + lr;
#pragma unroll
            for (int r = 0; r < 4; r++)
                Y[(size_t)(m0 + r) * HW + n] = acc[mf][f][r] + bias[m0 + r];
        }
    }
}

extern "C" void kernel_launch(void* const* d_in, const int* in_sizes, int n_in,
                              void* d_out, int out_size, void* d_ws, size_t ws_size,
                              hipStream_t stream) {
    const float* x      = (const float*)d_in[0];
    const float* wq     = (const float*)d_in[1];
    const float* w_qdw  = (const float*)d_in[2];
    const float* b_qdw  = (const float*)d_in[3];
    const float* wkv    = (const float*)d_in[4];
    const float* w_kvdw = (const float*)d_in[5];
    const float* b_kvdw = (const float*)d_in[6];
    const float* ln_w   = (const float*)d_in[7];
    const float* ln_b   = (const float*)d_in[8];
    const float* w_proj = (const float*)d_in[9];
    const float* b_proj = (const float*)d_in[10];
    float* out = (float*)d_out;
    char* ws = (char*)d_ws;

    // Pair-batched (z=2) ws layout, ~353 MB (ws_size >= 604 MB proven r7):
    __hip_bfloat16* qkv0  = (__hip_bfloat16*)(ws + 0);
    __hip_bfloat16* kvbuf = (__hip_bfloat16*)(ws + 150994944ull);
    __hip_bfloat16* sbuf  = (__hip_bfloat16*)(ws + 251658240ull);
    __hip_bfloat16* xT    = (__hip_bfloat16*)(ws + 301989888ull);
    __hip_bfloat16* Wqkv  = (__hip_bfloat16*)(ws + 352321536ull);
    __hip_bfloat16* Wp    = Wqkv + 110592;

    pack_weights<<<576, 256, 0, stream>>>(wq, wkv, w_proj, Wqkv, Wp);

    for (int p = 0; p < 2; p++) {
        const float* xp = x + (size_t)(p * 2) * BS_X;
        float* outp = out + (size_t)(p * 2) * BS_OUT;
        transpose_cvt<<<dim3(HW / 32, 6, 2), 256, 0, stream>>>(xp, xT);
        gemm_bf16<<<dim3(9, HW / 64, 2), 256, 0, stream>>>(Wqkv, xT, qkv0);
        dwconv7_v8<<<dim3(2, 384, 2), 256, 0, stream>>>(qkv0 + (size_t)192 * HW,
                                                        w_kvdw, b_kvdw, kvbuf);
        circ_qfused<<<dim3(8, 192, 2), 256, 0, stream>>>(qkv0, kvbuf,
                                                         w_qdw, b_qdw, sbuf);
        gemm_proj_ln<<<dim3(HW / 128, 1, 2), 256, 0, stream>>>(
            Wp, sbuf, kvbuf + (size_t)192 * HW, ln_w, ln_b, b_proj, outp);
    }
}